// Round 9
// baseline (97.914 us; speedup 1.0000x reference)
//
#include <hip/hip_runtime.h>

#define BIG 1e20f
#define LOG2E 1.44269504088896f

// Fused kernel: one block per (b, channel-PAIR) -> 1024 blocks x 512 threads.
// Each thread owns 8 CONSECUTIVE l (512*8 = 4096 = full row) for two channels.
// Softmax weights computed inline from delta_time, pre-scaled by log2e so the
// weight exp is a single v_exp_f32 (exp2f). Threads with l>=8 skip the
// max-subtract (all taps real, args bounded => shift-invariance makes it
// redundant); tid 0 keeps the sentinel+max path to reproduce the reference's
// BIG-masked softmax exactly (masked taps weight 1/M, real taps 0, x=0).
__global__ __launch_bounds__(512) void fused_kernel(const float* __restrict__ x,
                                                    const float* __restrict__ dt,
                                                    const float* __restrict__ ker,
                                                    float* __restrict__ out,
                                                    int C, int L) {
    const int pair = blockIdx.x;        // b * 128 + c/2
    const int b    = pair >> 7;         // C/2 = 128 pairs per batch
    const int c0   = (pair & 127) << 1;
    const int tid  = threadIdx.x;
    const int l0   = tid * 8;           // outputs l0 .. l0+7

    const float* x0  = x + ((size_t)b * C + c0) * L;
    const float* x1  = x0 + L;
    const float* dtb = dt + (size_t)b * L;
    float*       o0  = out + ((size_t)b * C + c0) * L;
    float*       o1  = o0 + L;

    float kk[8];
#pragma unroll
    for (int k = 0; k < 8; ++k) kk[k] = ker[k];

    // Windows: slot i holds position l0 - 8 + i, i in [0,16).
    float xr0[16], xr1[16], dtr[16];
    if (tid == 0) {
#pragma unroll
        for (int i = 0; i < 8; ++i) { xr0[i] = 0.f; xr1[i] = 0.f; dtr[i] = BIG; }
    } else {
        float4 a0 = *reinterpret_cast<const float4*>(x0 + l0 - 8);
        float4 a1 = *reinterpret_cast<const float4*>(x0 + l0 - 4);
        xr0[0] = a0.x; xr0[1] = a0.y; xr0[2] = a0.z; xr0[3] = a0.w;
        xr0[4] = a1.x; xr0[5] = a1.y; xr0[6] = a1.z; xr0[7] = a1.w;
        float4 b0 = *reinterpret_cast<const float4*>(x1 + l0 - 8);
        float4 b1 = *reinterpret_cast<const float4*>(x1 + l0 - 4);
        xr1[0] = b0.x; xr1[1] = b0.y; xr1[2] = b0.z; xr1[3] = b0.w;
        xr1[4] = b1.x; xr1[5] = b1.y; xr1[6] = b1.z; xr1[7] = b1.w;
        float4 d0 = *reinterpret_cast<const float4*>(dtb + l0 - 8);
        float4 d1 = *reinterpret_cast<const float4*>(dtb + l0 - 4);
        dtr[0] = d0.x; dtr[1] = d0.y; dtr[2] = d0.z; dtr[3] = d0.w;
        dtr[4] = d1.x; dtr[5] = d1.y; dtr[6] = d1.z; dtr[7] = d1.w;
    }
    {
        float4 a2 = *reinterpret_cast<const float4*>(x0 + l0);
        float4 a3 = *reinterpret_cast<const float4*>(x0 + l0 + 4);
        xr0[8]  = a2.x; xr0[9]  = a2.y; xr0[10] = a2.z; xr0[11] = a2.w;
        xr0[12] = a3.x; xr0[13] = a3.y; xr0[14] = a3.z; xr0[15] = a3.w;
        float4 b2 = *reinterpret_cast<const float4*>(x1 + l0);
        float4 b3 = *reinterpret_cast<const float4*>(x1 + l0 + 4);
        xr1[8]  = b2.x; xr1[9]  = b2.y; xr1[10] = b2.z; xr1[11] = b2.w;
        xr1[12] = b3.x; xr1[13] = b3.y; xr1[14] = b3.z; xr1[15] = b3.w;
        float4 d2 = *reinterpret_cast<const float4*>(dtb + l0);
        float4 d3 = *reinterpret_cast<const float4*>(dtb + l0 + 4);
        dtr[8]  = d2.x; dtr[9]  = d2.y; dtr[10] = d2.z; dtr[11] = d2.w;
        dtr[12] = d3.x; dtr[13] = d3.y; dtr[14] = d3.z; dtr[15] = d3.w;
    }

    // Pre-scale dt window: softmax_e(v) == softmax_2(v * log2e).
#pragma unroll
    for (int i = 0; i < 16; ++i) dtr[i] *= LOG2E;

    float tv0[8], pv0[8], tv1[8], pv1[8];
    float gr[6] = {0.f, 0.f, 0.f, 0.f, 0.f, 0.f};   // tt0,tp0,pp0,tt1,tp1,pp1

#pragma unroll
    for (int j = 0; j < 8; ++j) {
        const float dtl = dtr[8 + j];
        float v[8];
#pragma unroll
        for (int k = 0; k < 8; ++k) v[k] = dtr[8 + j - k] - dtl;
        if (tid == 0) {
            // Sentinel path: max-subtract so masked taps (BIG) -> weight 1/M,
            // real taps -> exp2(-BIG) = 0, matching the reference exactly.
            float m = v[0];
#pragma unroll
            for (int k = 1; k < 8; ++k) m = fmaxf(m, v[k]);
#pragma unroll
            for (int k = 0; k < 8; ++k) v[k] -= m;
        }
        float s = 0.f;
#pragma unroll
        for (int k = 0; k < 8; ++k) { v[k] = exp2f(v[k]); s += v[k]; }
        const float inv = 1.f / s;

        float t0 = 0.f, p0 = 0.f, t1 = 0.f, p1 = 0.f;
#pragma unroll
        for (int k = 0; k < 8; ++k) {
            const float wk = v[k] * inv;
            const float xa = xr0[8 + j - k];
            const float xb = xr1[8 + j - k];
            t0 = fmaf(xa, wk, t0);
            p0 = fmaf(xa, kk[k], p0);
            t1 = fmaf(xb, wk, t1);
            p1 = fmaf(xb, kk[k], p1);
        }
        tv0[j] = t0;  pv0[j] = p0;
        tv1[j] = t1;  pv1[j] = p1;
        gr[0] = fmaf(t0, t0, gr[0]);
        gr[1] = fmaf(t0, p0, gr[1]);
        gr[2] = fmaf(p0, p0, gr[2]);
        gr[3] = fmaf(t1, t1, gr[3]);
        gr[4] = fmaf(t1, p1, gr[4]);
        gr[5] = fmaf(p1, p1, gr[5]);
    }

    // Block-reduce 6 Gram scalars: wave butterfly + 8-wave LDS combine.
#pragma unroll
    for (int off = 32; off > 0; off >>= 1) {
#pragma unroll
        for (int i = 0; i < 6; ++i) gr[i] += __shfl_down(gr[i], off);
    }
    __shared__ float red[6][8];
    const int wave = tid >> 6;
    if ((tid & 63) == 0) {
#pragma unroll
        for (int i = 0; i < 6; ++i) red[i][wave] = gr[i];
    }
    __syncthreads();
    float G[6];
#pragma unroll
    for (int i = 0; i < 6; ++i) {
        float acc = 0.f;
#pragma unroll
        for (int wv = 0; wv < 8; ++wv) acc += red[i][wv];
        G[i] = acc;
    }

    // Per-channel row-softmax of [[Gtt,Gtp],[Gtp,Gpp]]; out = ct*t + cp*p.
    float ct[2], cp[2];
#pragma unroll
    for (int ch = 0; ch < 2; ++ch) {
        const float Gtt = G[ch * 3 + 0], Gtp = G[ch * 3 + 1], Gpp = G[ch * 3 + 2];
        const float m0 = fmaxf(Gtt, Gtp);
        const float e00 = __expf(Gtt - m0), e01 = __expf(Gtp - m0);
        const float r0 = 1.f / (e00 + e01);
        const float m1 = fmaxf(Gtp, Gpp);
        const float e10 = __expf(Gtp - m1), e11 = __expf(Gpp - m1);
        const float r1 = 1.f / (e10 + e11);
        ct[ch] = 0.5f * (e00 * r0 + e10 * r1);
        cp[ch] = 0.5f * (e01 * r0 + e11 * r1);
    }

    float4 oa, ob;
    oa.x = fmaf(ct[0], tv0[0], cp[0] * pv0[0]);
    oa.y = fmaf(ct[0], tv0[1], cp[0] * pv0[1]);
    oa.z = fmaf(ct[0], tv0[2], cp[0] * pv0[2]);
    oa.w = fmaf(ct[0], tv0[3], cp[0] * pv0[3]);
    *reinterpret_cast<float4*>(o0 + l0) = oa;
    ob.x = fmaf(ct[0], tv0[4], cp[0] * pv0[4]);
    ob.y = fmaf(ct[0], tv0[5], cp[0] * pv0[5]);
    ob.z = fmaf(ct[0], tv0[6], cp[0] * pv0[6]);
    ob.w = fmaf(ct[0], tv0[7], cp[0] * pv0[7]);
    *reinterpret_cast<float4*>(o0 + l0 + 4) = ob;

    oa.x = fmaf(ct[1], tv1[0], cp[1] * pv1[0]);
    oa.y = fmaf(ct[1], tv1[1], cp[1] * pv1[1]);
    oa.z = fmaf(ct[1], tv1[2], cp[1] * pv1[2]);
    oa.w = fmaf(ct[1], tv1[3], cp[1] * pv1[3]);
    *reinterpret_cast<float4*>(o1 + l0) = oa;
    ob.x = fmaf(ct[1], tv1[4], cp[1] * pv1[4]);
    ob.y = fmaf(ct[1], tv1[5], cp[1] * pv1[5]);
    ob.z = fmaf(ct[1], tv1[6], cp[1] * pv1[6]);
    ob.w = fmaf(ct[1], tv1[7], cp[1] * pv1[7]);
    *reinterpret_cast<float4*>(o1 + l0 + 4) = ob;
}

extern "C" void kernel_launch(void* const* d_in, const int* in_sizes, int n_in,
                              void* d_out, int out_size, void* d_ws, size_t ws_size,
                              hipStream_t stream) {
    const float* x   = (const float*)d_in[0];   // (8, 256, 4096)
    const float* dt  = (const float*)d_in[1];   // (8, 4096)
    const float* ker = (const float*)d_in[2];   // (1, 1, 8)
    float* out = (float*)d_out;                 // (8, 256, 4096)

    const int B = 8, C = 256, L = 4096;
    fused_kernel<<<(B * C) / 2, 512, 0, stream>>>(x, dt, ker, out, C, L);
}

// Round 12
// 94.489 us; speedup vs baseline: 1.0362x; 1.0362x over previous
//
#include <hip/hip_runtime.h>

#define BIG 1e20f
#define LOG2E 1.44269504088896f

// Fused kernel: one block per (b, channel-PAIR) -> 1024 blocks x 512 threads.
// Each thread owns 8 l as 2 groups of 4 CONSECUTIVE l (16B lane stride: every
// global load/store fully coalesced — round-8 structure, best measured).
// Softmax weights computed inline from delta_time (no w scratch, no 2nd
// kernel). VALU cuts: dt window pre-scaled by log2e so each weight-exp is a
// single v_exp_f32 (exp2f); the serial 7-fmax max-subtract chain runs ONLY on
// the two g=0 sentinel threads (l<8) where BIG sentinels require it — for all
// other threads softmax shift-invariance + bounded args (|dt diff|*log2e <
// 1.45) make it redundant.
__global__ __launch_bounds__(512) void fused_kernel(const float* __restrict__ x,
                                                    const float* __restrict__ dt,
                                                    const float* __restrict__ ker,
                                                    float* __restrict__ out,
                                                    int C, int L) {
    const int pair = blockIdx.x;        // b * 128 + c/2
    const int b    = pair >> 7;         // C/2 = 128 pairs per batch
    const int c0   = (pair & 127) << 1;
    const int tid  = threadIdx.x;

    const float* x0  = x + ((size_t)b * C + c0) * L;
    const float* x1  = x0 + L;
    const float* dtb = dt + (size_t)b * L;
    float*       o0  = out + ((size_t)b * C + c0) * L;
    float*       o1  = o0 + L;

    float kk[8];
#pragma unroll
    for (int k = 0; k < 8; ++k) kk[k] = ker[k];

    float tv0[8], pv0[8], tv1[8], pv1[8];
    float gr[6] = {0.f, 0.f, 0.f, 0.f, 0.f, 0.f};   // tt0,tp0,pp0,tt1,tp1,pp1

#pragma unroll
    for (int g = 0; g < 2; ++g) {
        const int l0 = g * 2048 + tid * 4;
        const bool sentinel = (g == 0 && tid < 2);   // l0 in {0,4}: masked taps

        // Windows: slot i holds position l0 - 8 + i, i in [0,12).
        float xr0[12], xr1[12], dtr[12];
        if (sentinel) {
            if (tid == 0) {
#pragma unroll
                for (int i = 0; i < 8; ++i) { xr0[i] = 0.f; xr1[i] = 0.f; dtr[i] = BIG; }
            } else {
#pragma unroll
                for (int i = 0; i < 4; ++i) { xr0[i] = 0.f; xr1[i] = 0.f; dtr[i] = BIG; }
                float4 a = *reinterpret_cast<const float4*>(x0 + 0);
                float4 bb = *reinterpret_cast<const float4*>(x1 + 0);
                float4 d = *reinterpret_cast<const float4*>(dtb + 0);
                xr0[4] = a.x;  xr0[5] = a.y;  xr0[6] = a.z;  xr0[7] = a.w;
                xr1[4] = bb.x; xr1[5] = bb.y; xr1[6] = bb.z; xr1[7] = bb.w;
                dtr[4] = d.x;  dtr[5] = d.y;  dtr[6] = d.z;  dtr[7] = d.w;
            }
        } else {
            float4 a0 = *reinterpret_cast<const float4*>(x0 + l0 - 8);
            float4 c4 = *reinterpret_cast<const float4*>(x0 + l0 - 4);
            xr0[0] = a0.x; xr0[1] = a0.y; xr0[2] = a0.z; xr0[3] = a0.w;
            xr0[4] = c4.x; xr0[5] = c4.y; xr0[6] = c4.z; xr0[7] = c4.w;
            float4 a1 = *reinterpret_cast<const float4*>(x1 + l0 - 8);
            float4 c1 = *reinterpret_cast<const float4*>(x1 + l0 - 4);
            xr1[0] = a1.x; xr1[1] = a1.y; xr1[2] = a1.z; xr1[3] = a1.w;
            xr1[4] = c1.x; xr1[5] = c1.y; xr1[6] = c1.z; xr1[7] = c1.w;
            float4 d0 = *reinterpret_cast<const float4*>(dtb + l0 - 8);
            float4 d1 = *reinterpret_cast<const float4*>(dtb + l0 - 4);
            dtr[0] = d0.x; dtr[1] = d0.y; dtr[2] = d0.z; dtr[3] = d0.w;
            dtr[4] = d1.x; dtr[5] = d1.y; dtr[6] = d1.z; dtr[7] = d1.w;
        }
        {
            float4 e0 = *reinterpret_cast<const float4*>(x0 + l0);
            xr0[8] = e0.x; xr0[9] = e0.y; xr0[10] = e0.z; xr0[11] = e0.w;
            float4 e1 = *reinterpret_cast<const float4*>(x1 + l0);
            xr1[8] = e1.x; xr1[9] = e1.y; xr1[10] = e1.z; xr1[11] = e1.w;
            float4 ed = *reinterpret_cast<const float4*>(dtb + l0);
            dtr[8] = ed.x; dtr[9] = ed.y; dtr[10] = ed.z; dtr[11] = ed.w;
        }

        // Pre-scale: softmax_e(v) == softmax_2(v * log2e).
#pragma unroll
        for (int i = 0; i < 12; ++i) dtr[i] *= LOG2E;

#pragma unroll
        for (int j = 0; j < 4; ++j) {
            const float dtl = dtr[8 + j];
            float v[8];
#pragma unroll
            for (int k = 0; k < 8; ++k) v[k] = dtr[8 + j - k] - dtl;
            if (sentinel) {
                // Max-subtract so masked taps (BIG) -> weight 1/M, real taps
                // -> exp2(-BIG) = 0, matching the reference's BIG semantics.
                float m = v[0];
#pragma unroll
                for (int k = 1; k < 8; ++k) m = fmaxf(m, v[k]);
#pragma unroll
                for (int k = 0; k < 8; ++k) v[k] -= m;
            }
            float s = 0.f;
#pragma unroll
            for (int k = 0; k < 8; ++k) { v[k] = exp2f(v[k]); s += v[k]; }
            const float inv = 1.f / s;

            float t0 = 0.f, p0 = 0.f, t1 = 0.f, p1 = 0.f;
#pragma unroll
            for (int k = 0; k < 8; ++k) {
                const float wk = v[k] * inv;
                const float xa = xr0[8 + j - k];
                const float xb = xr1[8 + j - k];
                t0 = fmaf(xa, wk, t0);
                p0 = fmaf(xa, kk[k], p0);
                t1 = fmaf(xb, wk, t1);
                p1 = fmaf(xb, kk[k], p1);
            }
            tv0[g * 4 + j] = t0;  pv0[g * 4 + j] = p0;
            tv1[g * 4 + j] = t1;  pv1[g * 4 + j] = p1;
            gr[0] = fmaf(t0, t0, gr[0]);
            gr[1] = fmaf(t0, p0, gr[1]);
            gr[2] = fmaf(p0, p0, gr[2]);
            gr[3] = fmaf(t1, t1, gr[3]);
            gr[4] = fmaf(t1, p1, gr[4]);
            gr[5] = fmaf(p1, p1, gr[5]);
        }
    }

    // Block-reduce 6 Gram scalars: wave butterfly + 8-wave LDS combine.
#pragma unroll
    for (int off = 32; off > 0; off >>= 1) {
#pragma unroll
        for (int i = 0; i < 6; ++i) gr[i] += __shfl_down(gr[i], off);
    }
    __shared__ float red[6][8];
    const int wave = tid >> 6;
    if ((tid & 63) == 0) {
#pragma unroll
        for (int i = 0; i < 6; ++i) red[i][wave] = gr[i];
    }
    __syncthreads();
    float G[6];
#pragma unroll
    for (int i = 0; i < 6; ++i) {
        float acc = 0.f;
#pragma unroll
        for (int wv = 0; wv < 8; ++wv) acc += red[i][wv];
        G[i] = acc;
    }

    // Per-channel row-softmax of [[Gtt,Gtp],[Gtp,Gpp]]; out = ct*t + cp*p.
    float ct[2], cp[2];
#pragma unroll
    for (int ch = 0; ch < 2; ++ch) {
        const float Gtt = G[ch * 3 + 0], Gtp = G[ch * 3 + 1], Gpp = G[ch * 3 + 2];
        const float m0 = fmaxf(Gtt, Gtp);
        const float e00 = __expf(Gtt - m0), e01 = __expf(Gtp - m0);
        const float r0 = 1.f / (e00 + e01);
        const float m1 = fmaxf(Gtp, Gpp);
        const float e10 = __expf(Gtp - m1), e11 = __expf(Gpp - m1);
        const float r1 = 1.f / (e10 + e11);
        ct[ch] = 0.5f * (e00 * r0 + e10 * r1);
        cp[ch] = 0.5f * (e01 * r0 + e11 * r1);
    }

#pragma unroll
    for (int g = 0; g < 2; ++g) {
        const int l0 = g * 2048 + tid * 4;
        float4 oa, ob;
        oa.x = fmaf(ct[0], tv0[g * 4 + 0], cp[0] * pv0[g * 4 + 0]);
        oa.y = fmaf(ct[0], tv0[g * 4 + 1], cp[0] * pv0[g * 4 + 1]);
        oa.z = fmaf(ct[0], tv0[g * 4 + 2], cp[0] * pv0[g * 4 + 2]);
        oa.w = fmaf(ct[0], tv0[g * 4 + 3], cp[0] * pv0[g * 4 + 3]);
        *reinterpret_cast<float4*>(o0 + l0) = oa;
        ob.x = fmaf(ct[1], tv1[g * 4 + 0], cp[1] * pv1[g * 4 + 0]);
        ob.y = fmaf(ct[1], tv1[g * 4 + 1], cp[1] * pv1[g * 4 + 1]);
        ob.z = fmaf(ct[1], tv1[g * 4 + 2], cp[1] * pv1[g * 4 + 2]);
        ob.w = fmaf(ct[1], tv1[g * 4 + 3], cp[1] * pv1[g * 4 + 3]);
        *reinterpret_cast<float4*>(o1 + l0) = ob;
    }
}

extern "C" void kernel_launch(void* const* d_in, const int* in_sizes, int n_in,
                              void* d_out, int out_size, void* d_ws, size_t ws_size,
                              hipStream_t stream) {
    const float* x   = (const float*)d_in[0];   // (8, 256, 4096)
    const float* dt  = (const float*)d_in[1];   // (8, 4096)
    const float* ker = (const float*)d_in[2];   // (1, 1, 8)
    float* out = (float*)d_out;                 // (8, 256, 4096)

    const int B = 8, C = 256, L = 4096;
    fused_kernel<<<(B * C) / 2, 512, 0, stream>>>(x, dt, ker, out, C, L);
}